// Round 3
// baseline (146.302 us; speedup 1.0000x reference)
//
#include <hip/hip_runtime.h>
#include <hip/hip_bf16.h>

// QLoRA fwd: y = x @ (NF4dequant(codes,absmax) + adapter)^T
// x [1048576, 64] f32; combined W [64,64]; y [1048576, 64] f32.
// Memory-bound: 268MB read + 268MB write -> ~85us floor @6.3TB/s copy ceiling.
// R3: R1's TLP (2048 blocks = 8 blk/CU = 32 waves/CU, launch_bounds(256,8))
//   + R2's ILP (explicit 2-deep rotating load pipeline, loads issued before
//     current strip's stores so waits are counted vmcnt, stores lag 1 iter)
//   + v_cvt_pk_bf16_f32 packing. NO non-temporal hints (R2 post-mortem:
//     NT inflated WRITE_SIZE 268->316MB and forfeited L3 read hits).

#define IN_F 64
#define OUT_F 64
#define N_TOKENS 1048576

typedef __attribute__((ext_vector_type(8))) short bf16x8;   // 8 bf16 (4 VGPRs)
typedef __attribute__((ext_vector_type(4))) float f32x4;    // 4 f32

__device__ __constant__ float NF4_CODE_D[16] = {
    -1.0f, -0.6961928009986877f, -0.5250730514526367f, -0.39491748809814453f,
    -0.28444138169288635f, -0.18477343022823334f, -0.09105003625154495f, 0.0f,
    0.07958029955625534f, 0.16093020141124725f, 0.24611230194568634f,
    0.33791524171829224f, 0.44070982933044434f, 0.5626170039176941f,
    0.7229568362236023f, 1.0f};

__device__ __forceinline__ unsigned short f32_to_bf16_rne(float f) {
    union { float f; unsigned int u; } v; v.f = f;
    unsigned int b = v.u + 0x7fffu + ((v.u >> 16) & 1u);
    return (unsigned short)(b >> 16);
}

// pack two f32 -> one dword of 2 bf16 (compiler emits v_cvt_pk_bf16_f32)
__device__ __forceinline__ unsigned int cvt2(float lo, float hi) {
    __hip_bfloat162 h = __float22bfloat162_rn(make_float2(lo, hi));
    union { __hip_bfloat162 h; unsigned int u; } c; c.h = h;
    return c.u;
}

union BF8 { bf16x8 v; unsigned int u[4]; };

// --- Kernel 1: combined weight dequant+adapter-add, 4096 elements ---
// BLOCKSIZE==IN_F==64 => NF4 block index b == output row o.
__global__ void dequant_weight_kernel(const int* __restrict__ codes,
                                      const float* __restrict__ absmax,
                                      const float* __restrict__ adapter,
                                      unsigned short* __restrict__ wbf) {
    int e = blockIdx.x * blockDim.x + threadIdx.x;
    if (e < OUT_F * IN_F) {
        int o = e >> 6;
        float w = NF4_CODE_D[codes[e]] * absmax[o] + adapter[e];
        wbf[e] = f32_to_bf16_rne(w);
    }
}

// --- Kernel 2: tall-skinny GEMM via MFMA 16x16x32 bf16 ---
// Per wave per strip of 16 tokens:
//   A-frag (W, regs): lane l holds W[j*16+(l&15)][s*32+(l>>4)*8 + 0..7]
//   B-frag (x):       lane l holds x[t0+(l&15)][s*32+(l>>4)*8 + 0..7]
//   D[o][t]: lane l -> token t0+(l&15), outs j*16+(l>>4)*4+r
// 8192 waves x 8 strips (strided), 2-deep rotating register pipeline.
__global__ __launch_bounds__(256, 8) void qlora_gemm_kernel(
    const float* __restrict__ x,
    const unsigned short* __restrict__ wbf,
    float* __restrict__ y) {

    const int lane  = threadIdx.x & 63;
    const int wave  = blockIdx.x * 4 + (threadIdx.x >> 6);
    const int row16 = lane & 15;
    const int kgrp  = lane >> 4;

    // Weight fragments, loaded once (8KB table, L2-resident).
    bf16x8 afrag[4][2];
#pragma unroll
    for (int j = 0; j < 4; ++j)
#pragma unroll
        for (int s = 0; s < 2; ++s)
            afrag[j][s] = *(const bf16x8*)(wbf + (j * 16 + row16) * 64 + s * 32 + kgrp * 8);

    // strip index walk: strip = wave + i*8192, i in [0,8)
    const long base = ((long)wave * 16 + row16) * 64;
    const float* xp = x + base + kgrp * 8;
    float*       yp = y + base + kgrp * 4;
    const long STEP = 8192L * 16 * 64;  // floats between successive strips of a wave

    // prologue: strip 0 loads
    f32x4 a0 = *(const f32x4*)(xp);
    f32x4 a1 = *(const f32x4*)(xp + 4);
    f32x4 a2 = *(const f32x4*)(xp + 32);
    f32x4 a3 = *(const f32x4*)(xp + 36);

#pragma unroll
    for (int i = 0; i < 8; ++i) {
        // issue next strip's loads FIRST (counted vmcnt; stores lag 1 iter)
        f32x4 n0 = a0, n1 = a1, n2 = a2, n3 = a3;
        if (i < 7) {
            const float* xn = xp + STEP;
            n0 = *(const f32x4*)(xn);
            n1 = *(const f32x4*)(xn + 4);
            n2 = *(const f32x4*)(xn + 32);
            n3 = *(const f32x4*)(xn + 36);
        }

        // convert current strip to bf16 B-fragments (v_cvt_pk_bf16_f32)
        BF8 b0, b1;
        b0.u[0] = cvt2(a0[0], a0[1]); b0.u[1] = cvt2(a0[2], a0[3]);
        b0.u[2] = cvt2(a1[0], a1[1]); b0.u[3] = cvt2(a1[2], a1[3]);
        b1.u[0] = cvt2(a2[0], a2[1]); b1.u[1] = cvt2(a2[2], a2[3]);
        b1.u[2] = cvt2(a3[0], a3[1]); b1.u[3] = cvt2(a3[2], a3[3]);

#pragma unroll
        for (int j = 0; j < 4; ++j) {
            f32x4 c = {0.f, 0.f, 0.f, 0.f};
            c = __builtin_amdgcn_mfma_f32_16x16x32_bf16(afrag[j][0], b0.v, c, 0, 0, 0);
            c = __builtin_amdgcn_mfma_f32_16x16x32_bf16(afrag[j][1], b1.v, c, 0, 0, 0);
            *(f32x4*)(yp + j * 16) = c;
        }

        xp += STEP; yp += STEP;
        a0 = n0; a1 = n1; a2 = n2; a3 = n3;  // rotate (named regs, static idx)
    }
}

extern "C" void kernel_launch(void* const* d_in, const int* in_sizes, int n_in,
                              void* d_out, int out_size, void* d_ws, size_t ws_size,
                              hipStream_t stream) {
    const float* x       = (const float*)d_in[0];
    const int*   codes   = (const int*)d_in[1];
    const float* absmax  = (const float*)d_in[2];
    const float* adapter = (const float*)d_in[3];
    float* y = (float*)d_out;
    unsigned short* wbf = (unsigned short*)d_ws;  // 64*64 bf16 = 8KB scratch

    dequant_weight_kernel<<<16, 256, 0, stream>>>(codes, absmax, adapter, wbf);

    // 2048 blocks x 256 thr = 8192 waves = 8 blocks/CU = 32 waves/CU.
    qlora_gemm_kernel<<<2048, 256, 0, stream>>>(x, wbf, y);
}

// Round 4
// 110.858 us; speedup vs baseline: 1.3197x; 1.3197x over previous
//
#include <hip/hip_runtime.h>
#include <hip/hip_bf16.h>

// QLoRA fwd: y = x @ (NF4dequant(codes,absmax) + adapter)^T
// x [1048576, 64] f32; combined W [64,64]; y [1048576, 64] f32.
// Memory-bound: 268MB read + 268MB write -> ~85us floor @6.3TB/s copy ceiling.
//
// R4: single fused kernel.
//  - W dequantized per-block into padded LDS (stride 36 dwords -> 2-way bank
//    aliasing = free). W-fragment reads are ds_read_b128 (lgkmcnt), so they
//    never serialize against the store queue (vmcnt).
//  - 2-deep register pipeline with #pragma unroll 1 (R3 post-mortem: full
//    unroll let LLVM hoist all 8 iterations' loads -> spills; forced 32 VGPR
//    cap made it worse). Loads of strip i+1 issue BEFORE stores of strip i,
//    so the cvt wait is counted vmcnt, stores drain one iteration behind.
//  - R1's proven grid: 2048 blk x 256 thr = 8 blk/CU = 32 waves/CU; strided
//    strip walk (dense moving front, good DRAM locality).
//  - No non-temporal hints (R2: WRITE inflated 268->316MB, L3 bypassed).

#define N_TOKENS 1048576
#define WROW 36  // LDS row stride in dwords (32 data + 4 pad)

typedef __attribute__((ext_vector_type(8))) short bf16x8;   // 8 bf16 (4 VGPRs)
typedef __attribute__((ext_vector_type(4))) float f32x4;    // 4 f32

__device__ __constant__ float NF4_CODE_D[16] = {
    -1.0f, -0.6961928009986877f, -0.5250730514526367f, -0.39491748809814453f,
    -0.28444138169288635f, -0.18477343022823334f, -0.09105003625154495f, 0.0f,
    0.07958029955625534f, 0.16093020141124725f, 0.24611230194568634f,
    0.33791524171829224f, 0.44070982933044434f, 0.5626170039176941f,
    0.7229568362236023f, 1.0f};

// pack two f32 -> one dword of 2 bf16 (v_cvt_pk_bf16_f32)
__device__ __forceinline__ unsigned int cvt2(float lo, float hi) {
    __hip_bfloat162 h = __float22bfloat162_rn(make_float2(lo, hi));
    union { __hip_bfloat162 h; unsigned int u; } c; c.h = h;
    return c.u;
}

union BF8 { bf16x8 v; unsigned int u[4]; };

// compute + store one 16-token strip (8 MFMA, 4 float4 stores)
__device__ __forceinline__ void strip_compute(
    f32x4 a0, f32x4 a1, f32x4 a2, f32x4 a3,
    const unsigned int* __restrict__ wbase, float* __restrict__ yp) {
    BF8 b0, b1;
    b0.u[0] = cvt2(a0[0], a0[1]); b0.u[1] = cvt2(a0[2], a0[3]);
    b0.u[2] = cvt2(a1[0], a1[1]); b0.u[3] = cvt2(a1[2], a1[3]);
    b1.u[0] = cvt2(a2[0], a2[1]); b1.u[1] = cvt2(a2[2], a2[3]);
    b1.u[2] = cvt2(a3[0], a3[1]); b1.u[3] = cvt2(a3[2], a3[3]);
#pragma unroll
    for (int j = 0; j < 4; ++j) {
        // W frag (j,s): LDS row j*16+row16, dwords s*16 + kgrp*4 (folded in wbase)
        bf16x8 w0 = *(const bf16x8*)(wbase + j * 16 * WROW);
        bf16x8 w1 = *(const bf16x8*)(wbase + j * 16 * WROW + 16);
        f32x4 c = {0.f, 0.f, 0.f, 0.f};
        c = __builtin_amdgcn_mfma_f32_16x16x32_bf16(w0, b0.v, c, 0, 0, 0);
        c = __builtin_amdgcn_mfma_f32_16x16x32_bf16(w1, b1.v, c, 0, 0, 0);
        *(f32x4*)(yp + j * 16) = c;
    }
}

// Fused: per-block W dequant into LDS, then tall-skinny MFMA GEMM.
// A-frag (W): lane l holds W[j*16+(l&15)][s*32+(l>>4)*8 + 0..7]
// B-frag (x): lane l holds x[t0+(l&15)][s*32+(l>>4)*8 + 0..7]
// D[o][t]: lane l -> token t0+(l&15), outs j*16+(l>>4)*4+r -> float4 stores
__global__ __launch_bounds__(256) void qlora_fused_kernel(
    const float* __restrict__ x,
    const int* __restrict__ codes,
    const float* __restrict__ absmax,
    const float* __restrict__ adapter,
    float* __restrict__ y) {

    __shared__ unsigned int wlds[64 * WROW];  // 9216 B, padded rows

    const int tid = threadIdx.x;

    // --- dequant W into LDS (33KB of params, L2/L3-broadcast across blocks) ---
    // BLOCKSIZE==IN_F==64 => NF4 block index == output row. 2048 dwords total.
#pragma unroll
    for (int it = 0; it < 8; ++it) {
        int d = tid + it * 256;        // dword index 0..2047
        int r = d >> 5;                // row (32 dwords of data per row)
        int c = d & 31;
        int e = d * 2;                 // bf16-element index
        float am = absmax[r];
        float w0 = NF4_CODE_D[codes[e]]     * am + adapter[e];
        float w1 = NF4_CODE_D[codes[e + 1]] * am + adapter[e + 1];
        wlds[r * WROW + c] = cvt2(w0, w1);
    }
    __syncthreads();

    // --- main loop ---
    const int lane  = tid & 63;
    const int wave  = blockIdx.x * 4 + (tid >> 6);
    const int row16 = lane & 15;
    const int kgrp  = lane >> 4;

    const long base = ((long)wave * 16 + row16) * 64;
    const float* xp = x + base + kgrp * 8;
    float*       yp = y + base + kgrp * 4;
    const long STEP = 8192L * 16 * 64;  // floats between a wave's successive strips

    const unsigned int* wbase = &wlds[row16 * WROW + kgrp * 4];

    // prologue: strip 0 loads
    f32x4 a0 = *(const f32x4*)(xp);
    f32x4 a1 = *(const f32x4*)(xp + 4);
    f32x4 a2 = *(const f32x4*)(xp + 32);
    f32x4 a3 = *(const f32x4*)(xp + 36);

#pragma unroll 1
    for (int i = 0; i < 7; ++i) {
        // issue next strip's loads FIRST (queue: [L(i), S(i-1), L(i+1)] ->
        // consume-wait is vmcnt(8); stores never block)
        const float* xn = xp + STEP;
        f32x4 n0 = *(const f32x4*)(xn);
        f32x4 n1 = *(const f32x4*)(xn + 4);
        f32x4 n2 = *(const f32x4*)(xn + 32);
        f32x4 n3 = *(const f32x4*)(xn + 36);

        strip_compute(a0, a1, a2, a3, wbase, yp);

        xp += STEP; yp += STEP;
        a0 = n0; a1 = n1; a2 = n2; a3 = n3;
    }
    // epilogue: last strip, no prefetch
    strip_compute(a0, a1, a2, a3, wbase, yp);
}

extern "C" void kernel_launch(void* const* d_in, const int* in_sizes, int n_in,
                              void* d_out, int out_size, void* d_ws, size_t ws_size,
                              hipStream_t stream) {
    const float* x       = (const float*)d_in[0];
    const int*   codes   = (const int*)d_in[1];
    const float* absmax  = (const float*)d_in[2];
    const float* adapter = (const float*)d_in[3];
    float* y = (float*)d_out;

    // 2048 blocks x 256 thr = 8192 waves = 8 blocks/CU = 32 waves/CU.
    qlora_fused_kernel<<<2048, 256, 0, stream>>>(x, codes, absmax, adapter, y);
}

// Round 5
// 105.052 us; speedup vs baseline: 1.3927x; 1.0553x over previous
//
#include <hip/hip_runtime.h>
#include <hip/hip_bf16.h>

// QLoRA fwd: y = x @ (NF4dequant(codes,absmax) + adapter)^T
// x [1048576, 64] f32; combined W [64,64]; y [1048576, 64] f32.
// Memory-bound: 268MB read + 268MB write; float4-copy ceiling 6.29 TB/s.
//
// R5 = R4 + NON-TEMPORAL STORES ONLY.
// Mechanism: x (268MB) nearly fits the 256MB Infinity Cache; R3's
// FETCH_SIZE=207MB (<268) shows partial L3 residency across graph replays
// even with y competing. Streaming y past L3 (nt stores) leaves x as the
// sole L3 tenant -> read hits up, HBM mostly handles the write stream.
// Loads stay CACHED (R2's mistake was NT loads too, which forfeit L3).
//
// Carried from R4:
//  - single fused kernel; W dequantized per-block into padded LDS
//    (stride 36 dwords -> 2-way bank aliasing = free; ds_read=lgkmcnt,
//    decoupled from the store queue's vmcnt)
//  - 2-deep register pipeline, #pragma unroll 1 (R3: full unroll hoisted
//    all loads -> spills). Loads of strip i+1 issue before stores of
//    strip i -> counted vmcnt waits, stores drain one iter behind.
//  - 2048 blk x 256 thr = 8 blk/CU = 32 waves/CU (R2: half-occupancy
//    regression; MLP calc says keep TLP maxed).

#define N_TOKENS 1048576
#define WROW 36  // LDS row stride in dwords (32 data + 4 pad)

typedef __attribute__((ext_vector_type(8))) short bf16x8;   // 8 bf16 (4 VGPRs)
typedef __attribute__((ext_vector_type(4))) float f32x4;    // 4 f32

__device__ __constant__ float NF4_CODE_D[16] = {
    -1.0f, -0.6961928009986877f, -0.5250730514526367f, -0.39491748809814453f,
    -0.28444138169288635f, -0.18477343022823334f, -0.09105003625154495f, 0.0f,
    0.07958029955625534f, 0.16093020141124725f, 0.24611230194568634f,
    0.33791524171829224f, 0.44070982933044434f, 0.5626170039176941f,
    0.7229568362236023f, 1.0f};

// pack two f32 -> one dword of 2 bf16 (v_cvt_pk_bf16_f32)
__device__ __forceinline__ unsigned int cvt2(float lo, float hi) {
    __hip_bfloat162 h = __float22bfloat162_rn(make_float2(lo, hi));
    union { __hip_bfloat162 h; unsigned int u; } c; c.h = h;
    return c.u;
}

union BF8 { bf16x8 v; unsigned int u[4]; };

// compute + store one 16-token strip (8 MFMA, 4 float4 NT stores)
__device__ __forceinline__ void strip_compute(
    f32x4 a0, f32x4 a1, f32x4 a2, f32x4 a3,
    const unsigned int* __restrict__ wbase, float* __restrict__ yp) {
    BF8 b0, b1;
    b0.u[0] = cvt2(a0[0], a0[1]); b0.u[1] = cvt2(a0[2], a0[3]);
    b0.u[2] = cvt2(a1[0], a1[1]); b0.u[3] = cvt2(a1[2], a1[3]);
    b1.u[0] = cvt2(a2[0], a2[1]); b1.u[1] = cvt2(a2[2], a2[3]);
    b1.u[2] = cvt2(a3[0], a3[1]); b1.u[3] = cvt2(a3[2], a3[3]);
#pragma unroll
    for (int j = 0; j < 4; ++j) {
        // W frag (j,s): LDS row j*16+row16, dwords s*16 + kgrp*4 (folded in wbase)
        bf16x8 w0 = *(const bf16x8*)(wbase + j * 16 * WROW);
        bf16x8 w1 = *(const bf16x8*)(wbase + j * 16 * WROW + 16);
        f32x4 c = {0.f, 0.f, 0.f, 0.f};
        c = __builtin_amdgcn_mfma_f32_16x16x32_bf16(w0, b0.v, c, 0, 0, 0);
        c = __builtin_amdgcn_mfma_f32_16x16x32_bf16(w1, b1.v, c, 0, 0, 0);
        __builtin_nontemporal_store(c, (f32x4*)(yp + j * 16));  // y: stream past L3
    }
}

// Fused: per-block W dequant into LDS, then tall-skinny MFMA GEMM.
// A-frag (W): lane l holds W[j*16+(l&15)][s*32+(l>>4)*8 + 0..7]
// B-frag (x): lane l holds x[t0+(l&15)][s*32+(l>>4)*8 + 0..7]
// D[o][t]: lane l -> token t0+(l&15), outs j*16+(l>>4)*4+r -> float4 stores
__global__ __launch_bounds__(256) void qlora_fused_kernel(
    const float* __restrict__ x,
    const int* __restrict__ codes,
    const float* __restrict__ absmax,
    const float* __restrict__ adapter,
    float* __restrict__ y) {

    __shared__ unsigned int wlds[64 * WROW];  // 9216 B, padded rows

    const int tid = threadIdx.x;

    // --- dequant W into LDS (33KB of params, L2/L3-broadcast across blocks) ---
    // BLOCKSIZE==IN_F==64 => NF4 block index == output row. 2048 dwords total.
#pragma unroll
    for (int it = 0; it < 8; ++it) {
        int d = tid + it * 256;        // dword index 0..2047
        int r = d >> 5;                // row (32 data dwords per row)
        int c = d & 31;
        int e = d * 2;                 // bf16-element index
        float am = absmax[r];
        float w0 = NF4_CODE_D[codes[e]]     * am + adapter[e];
        float w1 = NF4_CODE_D[codes[e + 1]] * am + adapter[e + 1];
        wlds[r * WROW + c] = cvt2(w0, w1);
    }
    __syncthreads();

    // --- main loop ---
    const int lane  = tid & 63;
    const int wave  = blockIdx.x * 4 + (tid >> 6);
    const int row16 = lane & 15;
    const int kgrp  = lane >> 4;

    const long base = ((long)wave * 16 + row16) * 64;
    const float* xp = x + base + kgrp * 8;
    float*       yp = y + base + kgrp * 4;
    const long STEP = 8192L * 16 * 64;  // floats between a wave's successive strips

    const unsigned int* wbase = &wlds[row16 * WROW + kgrp * 4];

    // prologue: strip 0 loads (cached — we WANT x resident in L3)
    f32x4 a0 = *(const f32x4*)(xp);
    f32x4 a1 = *(const f32x4*)(xp + 4);
    f32x4 a2 = *(const f32x4*)(xp + 32);
    f32x4 a3 = *(const f32x4*)(xp + 36);

#pragma unroll 1
    for (int i = 0; i < 7; ++i) {
        // issue next strip's loads FIRST (queue: [L(i), S(i-1), L(i+1)] ->
        // consume-wait is counted vmcnt; stores never block)
        const float* xn = xp + STEP;
        f32x4 n0 = *(const f32x4*)(xn);
        f32x4 n1 = *(const f32x4*)(xn + 4);
        f32x4 n2 = *(const f32x4*)(xn + 32);
        f32x4 n3 = *(const f32x4*)(xn + 36);

        strip_compute(a0, a1, a2, a3, wbase, yp);

        xp += STEP; yp += STEP;
        a0 = n0; a1 = n1; a2 = n2; a3 = n3;
    }
    // epilogue: last strip, no prefetch
    strip_compute(a0, a1, a2, a3, wbase, yp);
}

extern "C" void kernel_launch(void* const* d_in, const int* in_sizes, int n_in,
                              void* d_out, int out_size, void* d_ws, size_t ws_size,
                              hipStream_t stream) {
    const float* x       = (const float*)d_in[0];
    const int*   codes   = (const int*)d_in[1];
    const float* absmax  = (const float*)d_in[2];
    const float* adapter = (const float*)d_in[3];
    float* y = (float*)d_out;

    // 2048 blocks x 256 thr = 8192 waves = 8 blocks/CU = 32 waves/CU.
    qlora_fused_kernel<<<2048, 256, 0, stream>>>(x, codes, absmax, adapter, y);
}

// Round 7
// 85.459 us; speedup vs baseline: 1.7120x; 1.2293x over previous
//
#include <hip/hip_runtime.h>
#include <hip/hip_bf16.h>

// QLoRA fwd: y = x @ (NF4dequant(codes,absmax) + adapter)^T
// x [1048576, 64] f32; combined W [64,64]; y [1048576, 64] f32.
// Memory-bound: 268MB read + 268MB write.
//
// R7 = R6 + WAVE-LEVEL LDS FENCES (R6 failed correctness: the y-staging
// transpose is a cross-lane LDS exchange; lane l reads what OTHER lanes
// wrote, so per-thread alias analysis sees no dependence -> compiler may
// reorder ds_write/ds_read or skip the lgkmcnt wait. Fix: explicit
// s_waitcnt lgkmcnt(0) + "memory" clobber between write->read and
// read->next write. DS ops can't cross a "memory" asm, unlike the
// register-only-MFMA case of rule #18.)
//
// Mechanism being exploited (R5/R6 evidence): fillBuffer's contiguous
// per-instruction stores show zero WRITE_SIZE inflation @7TB/s; our MFMA
// -layout stores (16x64B @256B stride per instr) inflated WRITE to
// 316-347MB via NT partial-line RMW. Staging each 16x64 strip through
// per-wave LDS and reading back linearly makes every NT store 64 lanes
// x 16B = 1KB contiguous full lines. NT stores keep y out of L3 so x
// stays L3-resident (R5: FETCH 207->131MB).
//
// Carried: fused dequant (W in padded LDS); cached x loads; 2-deep
// pipeline w/ #pragma unroll 1 (R3: unroll-hoist spills); 2048x256 grid
// = 8 blk/CU = 32 waves/CU (R2: half-occupancy regression).

#define N_TOKENS 1048576
#define WROW 36  // W LDS row stride (dwords): 32 data + 4 pad
#define YROW 68  // y-staging row stride (dwords): 64 data + 4 pad, 16B-aligned

typedef __attribute__((ext_vector_type(8))) short bf16x8;   // 8 bf16 (4 VGPRs)
typedef __attribute__((ext_vector_type(4))) float f32x4;    // 4 f32

// wave-level LDS exchange fence: pins DS program order (memory clobber)
// and waits for prior DS ops to complete (writes landed / reads returned).
#define LDS_XCHG_FENCE() asm volatile("s_waitcnt lgkmcnt(0)" ::: "memory")

__device__ __constant__ float NF4_CODE_D[16] = {
    -1.0f, -0.6961928009986877f, -0.5250730514526367f, -0.39491748809814453f,
    -0.28444138169288635f, -0.18477343022823334f, -0.09105003625154495f, 0.0f,
    0.07958029955625534f, 0.16093020141124725f, 0.24611230194568634f,
    0.33791524171829224f, 0.44070982933044434f, 0.5626170039176941f,
    0.7229568362236023f, 1.0f};

// pack two f32 -> one dword of 2 bf16 (v_cvt_pk_bf16_f32)
__device__ __forceinline__ unsigned int cvt2(float lo, float hi) {
    __hip_bfloat162 h = __float22bfloat162_rn(make_float2(lo, hi));
    union { __hip_bfloat162 h; unsigned int u; } c; c.h = h;
    return c.u;
}

union BF8 { bf16x8 v; unsigned int u[4]; };

// Fused: per-block W dequant into LDS, tall-skinny MFMA GEMM, LDS-transposed
// contiguous stores.
// A-frag (W): lane l holds W[j*16+(l&15)][s*32+(l>>4)*8 + 0..7]
// B-frag (x): lane l holds x[t0+(l&15)][s*32+(l>>4)*8 + 0..7]
// D[o][t]:    lane l -> token t0+(l&15), outs j*16+(l>>4)*4+r
__global__ __launch_bounds__(256) void qlora_fused_kernel(
    const float* __restrict__ x,
    const int* __restrict__ codes,
    const float* __restrict__ absmax,
    const float* __restrict__ adapter,
    float* __restrict__ y) {

    __shared__ unsigned int wlds[64 * WROW];                 // 9216 B
    __shared__ __align__(16) unsigned int ylds[4][8 * YROW]; // 8704 B

    const int tid = threadIdx.x;

    // --- dequant W into LDS (33KB of params, L2/L3-broadcast) ---
#pragma unroll
    for (int it = 0; it < 8; ++it) {
        int d = tid + it * 256;        // dword index 0..2047
        int r = d >> 5;                // row (32 data dwords per row)
        int c = d & 31;
        int e = d * 2;                 // bf16-element index
        float am = absmax[r];
        float w0 = NF4_CODE_D[codes[e]]     * am + adapter[e];
        float w1 = NF4_CODE_D[codes[e + 1]] * am + adapter[e + 1];
        wlds[r * WROW + c] = cvt2(w0, w1);
    }
    __syncthreads();

    // --- main loop ---
    const int lane  = tid & 63;
    const int wv    = tid >> 6;
    const int wave  = blockIdx.x * 4 + wv;
    const int row16 = lane & 15;
    const int kgrp  = lane >> 4;

    const long base = ((long)wave * 16 + row16) * 64;
    const float* xp = x + base + kgrp * 8;
    const long STEP = 8192L * 16 * 64;  // dwords between a wave's strips

    // y store: per strip, 2 passes x 2 stores of 1KB contiguous each
    float* yp = y + (long)wave * 1024 + lane * 4;

    const unsigned int* wbase = &wlds[row16 * WROW + kgrp * 4];
    const int mypass = row16 >> 3;                 // which pass owns my token
    unsigned int* ywr = &ylds[wv][(row16 & 7) * YROW + kgrp * 4];
    const unsigned int* yrd = &ylds[wv][(lane >> 4) * YROW + (lane & 15) * 4];

    // prologue: strip 0 loads (cached — keep x L3-resident)
    f32x4 a0 = *(const f32x4*)(xp);
    f32x4 a1 = *(const f32x4*)(xp + 4);
    f32x4 a2 = *(const f32x4*)(xp + 32);
    f32x4 a3 = *(const f32x4*)(xp + 36);

#pragma unroll 1
    for (int i = 0; i < 8; ++i) {
        // convert current strip (consumes a*)
        BF8 b0, b1;
        b0.u[0] = cvt2(a0[0], a0[1]); b0.u[1] = cvt2(a0[2], a0[3]);
        b0.u[2] = cvt2(a1[0], a1[1]); b0.u[3] = cvt2(a1[2], a1[3]);
        b1.u[0] = cvt2(a2[0], a2[1]); b1.u[1] = cvt2(a2[2], a2[3]);
        b1.u[2] = cvt2(a3[0], a3[1]); b1.u[3] = cvt2(a3[2], a3[3]);

        // next strip's loads into a* NOW — before this strip's stores, so
        // consume-waits stay counted vmcnt and stores drain one iter behind
        if (i < 7) {
            const float* xn = xp + STEP;
            a0 = *(const f32x4*)(xn);
            a1 = *(const f32x4*)(xn + 4);
            a2 = *(const f32x4*)(xn + 32);
            a3 = *(const f32x4*)(xn + 36);
            xp += STEP;
        }

        // MFMA: acc[j] = this lane's token row, outs j*16+kgrp*4+{0..3}
        f32x4 acc[4];
#pragma unroll
        for (int j = 0; j < 4; ++j) {
            bf16x8 w0 = *(const bf16x8*)(wbase + j * 16 * WROW);
            bf16x8 w1 = *(const bf16x8*)(wbase + j * 16 * WROW + 16);
            f32x4 c = {0.f, 0.f, 0.f, 0.f};
            c = __builtin_amdgcn_mfma_f32_16x16x32_bf16(w0, b0.v, c, 0, 0, 0);
            c = __builtin_amdgcn_mfma_f32_16x16x32_bf16(w1, b1.v, c, 0, 0, 0);
            acc[j] = c;
        }

        // stage through LDS, store contiguous 1KB lines (fillBuffer pattern)
        float* yps = yp + (long)i * STEP;
#pragma unroll
        for (int p = 0; p < 2; ++p) {
            if (mypass == p) {
#pragma unroll
                for (int j = 0; j < 4; ++j)
                    *(f32x4*)(ywr + j * 16) = acc[j];
            }
            // cross-lane exchange: writes must land before any lane reads
            LDS_XCHG_FENCE();
#pragma unroll
            for (int s = 0; s < 2; ++s) {
                f32x4 v = *(const f32x4*)(yrd + s * 4 * YROW);
                __builtin_nontemporal_store(v, (f32x4*)(yps + p * 512 + s * 256));
            }
            // reads must return before next pass/iter overwrites (WAR)
            LDS_XCHG_FENCE();
        }
    }
}

extern "C" void kernel_launch(void* const* d_in, const int* in_sizes, int n_in,
                              void* d_out, int out_size, void* d_ws, size_t ws_size,
                              hipStream_t stream) {
    const float* x       = (const float*)d_in[0];
    const int*   codes   = (const int*)d_in[1];
    const float* absmax  = (const float*)d_in[2];
    const float* adapter = (const float*)d_in[3];
    float* y = (float*)d_out;

    // 2048 blocks x 256 thr = 8192 waves = 8 blocks/CU = 32 waves/CU.
    qlora_fused_kernel<<<2048, 256, 0, stream>>>(x, codes, absmax, adapter, y);
}